// Round 1
// baseline (5999.880 us; speedup 1.0000x reference)
//
#include <hip/hip_runtime.h>
#include <hip/hip_bf16.h>
#include <math.h>

// Problem constants
// B=64, S=128, V=50257, E=1024, H=1024, G=3H=3072
#define GRU_B 64
#define GRU_S 128
#define GRU_E 1024
#define GRU_H 1024
#define GRU_G 3072

// ---------------------------------------------------------------------------
// Phase 1: x_proj[s][b][g] = b_ih[g] + sum_e emb[tok[b][s]][e] * w_ih[g][e]
// GEMM M=8192 (m = s*64+b), N=3072, K=1024, with gathered A rows.
// 64x64 C-tile, 256 threads, 4x4 register tile, K-chunk 16.
// grid = (128 m-tiles, 48 n-tiles). One m-tile == one s (64 batches).
// ---------------------------------------------------------------------------
__global__ __launch_bounds__(256) void xproj_gemm(
    const int* __restrict__ tokens,     // [B][S] (b-major, stride S)
    const float* __restrict__ emb,      // [V][E]
    const float* __restrict__ w_ih,     // [G][E]
    const float* __restrict__ b_ih,     // [G]
    float* __restrict__ xproj)          // [S][B][G]
{
    __shared__ float As[64][17];   // [m_local][k]
    __shared__ float Bs[64][17];   // [n_local][k]
    __shared__ int   toks[64];

    const int t  = threadIdx.x;
    const int s  = blockIdx.x;          // m-tile == one timestep
    const int n0 = blockIdx.y * 64;

    if (t < 64) toks[t] = tokens[t * GRU_S + s];   // tokens[b][s], b = t
    __syncthreads();

    const int tm = t >> 4;   // 0..15
    const int tn = t & 15;   // 0..15

    float acc[4][4];
#pragma unroll
    for (int i = 0; i < 4; ++i)
#pragma unroll
        for (int j = 0; j < 4; ++j) acc[i][j] = 0.f;

    for (int k0 = 0; k0 < GRU_E; k0 += 16) {
#pragma unroll
        for (int q = 0; q < 4; ++q) {
            int idx = t + q * 256;          // 0..1023
            int row = idx >> 4;             // 0..63
            int kk  = idx & 15;
            As[row][kk] = emb[(size_t)toks[row] * GRU_E + k0 + kk];
            Bs[row][kk] = w_ih[(size_t)(n0 + row) * GRU_E + k0 + kk];
        }
        __syncthreads();

#pragma unroll
        for (int kk = 0; kk < 16; ++kk) {
            float a[4], b[4];
#pragma unroll
            for (int i = 0; i < 4; ++i) a[i] = As[tm * 4 + i][kk];
#pragma unroll
            for (int j = 0; j < 4; ++j) b[j] = Bs[tn * 4 + j][kk];
#pragma unroll
            for (int i = 0; i < 4; ++i)
#pragma unroll
                for (int j = 0; j < 4; ++j)
                    acc[i][j] = fmaf(a[i], b[j], acc[i][j]);
        }
        __syncthreads();
    }

    // epilogue: add b_ih, write x_proj (row m = s*64+b, col n)
#pragma unroll
    for (int i = 0; i < 4; ++i) {
        int m = s * 64 + tm * 4 + i;
#pragma unroll
        for (int j = 0; j < 4; ++j) {
            int n = n0 + tn * 4 + j;
            xproj[(size_t)m * GRU_G + n] = acc[i][j] + b_ih[n];
        }
    }
}

// ---------------------------------------------------------------------------
// Phase 2: one GRU step.
//   hp = h_in @ w_hh^T + b_hh      (64 x 3072)
//   r = sigmoid(xr + hp_r); z = sigmoid(xz + hp_z); n = tanh(xn + r*hp_n)
//   h_out = (1-z)*n + z*h_in
// grid = (4 b-tiles, 64 j-tiles), 256 threads, 1 output (b,j) per thread,
// 3 fused dot products of length 1024 from LDS-staged tiles.
// ---------------------------------------------------------------------------
__global__ __launch_bounds__(256) void gru_step(
    const float* __restrict__ h_in,     // [B][H]
    const float* __restrict__ xp_s,     // [B][G]  (x_proj slab for this s)
    const float* __restrict__ w_hh,     // [G][H]
    const float* __restrict__ b_hh,     // [G]
    float* __restrict__ h_out)          // [B][H]
{
    __shared__ float hs [16][33];
    __shared__ float wrs[16][33];
    __shared__ float wzs[16][33];
    __shared__ float wns[16][33];

    const int t  = threadIdx.x;
    const int b0 = blockIdx.x * 16;     // batch tile
    const int j0 = blockIdx.y * 16;     // hidden-unit tile
    const int bb = t >> 4;              // 0..15
    const int jj = t & 15;              // 0..15

    const int lrow = t >> 5;            // 0..7 (staging)
    const int lcol = t & 31;            // 0..31

    float ar = 0.f, az = 0.f, an = 0.f;

    for (int e0 = 0; e0 < GRU_H; e0 += 32) {
        hs [lrow    ][lcol] = h_in[(size_t)(b0 + lrow    ) * GRU_H + e0 + lcol];
        hs [lrow + 8][lcol] = h_in[(size_t)(b0 + lrow + 8) * GRU_H + e0 + lcol];
        wrs[lrow    ][lcol] = w_hh[(size_t)(           j0 + lrow    ) * GRU_H + e0 + lcol];
        wrs[lrow + 8][lcol] = w_hh[(size_t)(           j0 + lrow + 8) * GRU_H + e0 + lcol];
        wzs[lrow    ][lcol] = w_hh[(size_t)(GRU_H    + j0 + lrow    ) * GRU_H + e0 + lcol];
        wzs[lrow + 8][lcol] = w_hh[(size_t)(GRU_H    + j0 + lrow + 8) * GRU_H + e0 + lcol];
        wns[lrow    ][lcol] = w_hh[(size_t)(2*GRU_H  + j0 + lrow    ) * GRU_H + e0 + lcol];
        wns[lrow + 8][lcol] = w_hh[(size_t)(2*GRU_H  + j0 + lrow + 8) * GRU_H + e0 + lcol];
        __syncthreads();

#pragma unroll
        for (int ee = 0; ee < 32; ++ee) {
            float hv = hs[bb][ee];
            ar = fmaf(hv, wrs[jj][ee], ar);
            az = fmaf(hv, wzs[jj][ee], az);
            an = fmaf(hv, wns[jj][ee], an);
        }
        __syncthreads();
    }

    const int b = b0 + bb;
    const int j = j0 + jj;

    float hr = ar + b_hh[j];
    float hz = az + b_hh[GRU_H + j];
    float hn = an + b_hh[2 * GRU_H + j];

    const float* xrow = xp_s + (size_t)b * GRU_G;
    float xr = xrow[j];
    float xz = xrow[GRU_H + j];
    float xn = xrow[2 * GRU_H + j];

    float r = 1.f / (1.f + expf(-(xr + hr)));
    float z = 1.f / (1.f + expf(-(xz + hz)));
    float n = tanhf(xn + r * hn);

    float hprev = h_in[(size_t)b * GRU_H + j];
    h_out[(size_t)b * GRU_H + j] = (1.f - z) * n + z * hprev;
}

// ---------------------------------------------------------------------------
// Launch
// ---------------------------------------------------------------------------
extern "C" void kernel_launch(void* const* d_in, const int* in_sizes, int n_in,
                              void* d_out, int out_size, void* d_ws, size_t ws_size,
                              hipStream_t stream) {
    const int*   tokens = (const int*)  d_in[0];
    const float* emb    = (const float*)d_in[1];
    const float* w_ih   = (const float*)d_in[2];
    const float* w_hh   = (const float*)d_in[3];
    const float* b_ih   = (const float*)d_in[4];
    const float* b_hh   = (const float*)d_in[5];
    float* out = (float*)d_out;

    // workspace layout
    float* xproj = (float*)d_ws;                                   // S*B*G floats = 96 MB
    float* h0    = xproj + (size_t)GRU_S * GRU_B * GRU_G;          // B*H floats
    float* h1    = h0 + (size_t)GRU_B * GRU_H;

    // h(0) = 0
    hipMemsetAsync(h0, 0, (size_t)GRU_B * GRU_H * sizeof(float), stream);

    // Phase 1: x_proj
    {
        dim3 grid(GRU_S, GRU_G / 64);   // 128 x 48
        xproj_gemm<<<grid, 256, 0, stream>>>(tokens, emb, w_ih, b_ih, xproj);
    }

    // Phase 2: 128 sequential GRU steps (ping-pong h buffers, last writes d_out)
    for (int s = 0; s < GRU_S; ++s) {
        const float* hin  = (s & 1) ? h1 : h0;
        float*       hout = (s == GRU_S - 1) ? out : ((s & 1) ? h0 : h1);
        const float* xps  = xproj + (size_t)s * GRU_B * GRU_G;
        gru_step<<<dim3(GRU_B / 16, GRU_H / 16), 256, 0, stream>>>(
            hin, xps, w_hh, b_hh, hout);
    }
}

// Round 2
// 3704.788 us; speedup vs baseline: 1.6195x; 1.6195x over previous
//
#include <hip/hip_runtime.h>
#include <hip/hip_bf16.h>
#include <math.h>

// B=64, S=128, V=50257, E=1024, H=1024, G=3H=3072
#define GRU_B 64
#define GRU_S 128
#define GRU_E 1024
#define GRU_H 1024
#define GRU_G 3072

// ---------------------------------------------------------------------------
// Phase 1: x_proj[m][g] = b_ih[g] + sum_e emb[tok[m]][e] * w_ih[g][e]
//   m = s*64+b  (M=8192), g (N=3072), e (K=1024)
// 128x128 C-tile, 256 threads, 8x8 register tile, K-chunk 32,
// LDS stored transposed As[kk][m] so fragment loads are ds_read_b128.
// ---------------------------------------------------------------------------
__global__ __launch_bounds__(256) void xproj_gemm2(
    const int* __restrict__ tokens,     // [B][S]
    const float* __restrict__ emb,      // [V][E]
    const float* __restrict__ w_ih,     // [G][E]
    const float* __restrict__ b_ih,     // [G]
    float* __restrict__ xproj)          // [M][G] == [S][B][G]
{
    __shared__ float As[32][132];
    __shared__ float Bs[32][132];
    __shared__ int   toks[128];

    const int t  = threadIdx.x;
    const int m0 = blockIdx.x * 128;    // 64 m-tiles
    const int n0 = blockIdx.y * 128;    // 24 n-tiles

    if (t < 128) {
        int m  = m0 + t;
        int s_ = m >> 6;
        int b_ = m & 63;
        toks[t] = tokens[b_ * GRU_S + s_];
    }

    const int tm = t >> 4;   // 0..15
    const int tn = t & 15;   // 0..15

    float acc[8][8] = {};

    const int srow_base = t >> 3;   // 0..31 (per q add 32)
    const int sc4       = t & 7;    // float4 column

    for (int k0 = 0; k0 < GRU_E; k0 += 32) {
        __syncthreads();   // also covers toks on first iter
#pragma unroll
        for (int q = 0; q < 4; ++q) {
            int row = q * 32 + srow_base;            // 0..127
            const float4 av = reinterpret_cast<const float4*>(
                emb + (size_t)toks[row] * GRU_E + k0)[sc4];
            const float4 bv = reinterpret_cast<const float4*>(
                w_ih + (size_t)(n0 + row) * GRU_E + k0)[sc4];
            int kk = sc4 * 4;
            As[kk+0][row] = av.x; As[kk+1][row] = av.y;
            As[kk+2][row] = av.z; As[kk+3][row] = av.w;
            Bs[kk+0][row] = bv.x; Bs[kk+1][row] = bv.y;
            Bs[kk+2][row] = bv.z; Bs[kk+3][row] = bv.w;
        }
        __syncthreads();

#pragma unroll 8
        for (int kk = 0; kk < 32; ++kk) {
            float a[8], bb[8];
            *reinterpret_cast<float4*>(&a[0])  = *reinterpret_cast<const float4*>(&As[kk][tm*8]);
            *reinterpret_cast<float4*>(&a[4])  = *reinterpret_cast<const float4*>(&As[kk][tm*8+4]);
            *reinterpret_cast<float4*>(&bb[0]) = *reinterpret_cast<const float4*>(&Bs[kk][tn*8]);
            *reinterpret_cast<float4*>(&bb[4]) = *reinterpret_cast<const float4*>(&Bs[kk][tn*8+4]);
#pragma unroll
            for (int i = 0; i < 8; ++i)
#pragma unroll
                for (int j = 0; j < 8; ++j)
                    acc[i][j] = fmaf(a[i], bb[j], acc[i][j]);
        }
    }

    float bias[8];
#pragma unroll
    for (int j = 0; j < 8; ++j) bias[j] = b_ih[n0 + tn*8 + j];

#pragma unroll
    for (int i = 0; i < 8; ++i) {
        int m = m0 + tm*8 + i;
        float4* dst = reinterpret_cast<float4*>(xproj + (size_t)m * GRU_G + n0 + tn*8);
        dst[0] = make_float4(acc[i][0]+bias[0], acc[i][1]+bias[1],
                             acc[i][2]+bias[2], acc[i][3]+bias[3]);
        dst[1] = make_float4(acc[i][4]+bias[4], acc[i][5]+bias[5],
                             acc[i][6]+bias[6], acc[i][7]+bias[7]);
    }
}

// ---------------------------------------------------------------------------
// Phase 2: one GRU step, 256 blocks x 256 threads (1 block/CU).
// Block jb owns j = jb*4 + {0..3} across all 3 gates: 12 w_hh rows in LDS
// (48 KB, staged once). h staged in 4 chunks of 256 e (64 KB, XOR-swizzled
// float4 slots -> conflict-free ds_read_b128). Thread (b=t&63, jj=t>>6)
// computes ar/az/an dots and fuses the gates.
// ---------------------------------------------------------------------------
__global__ __launch_bounds__(256) void gru_step2(
    const float* __restrict__ h_in,     // [64][1024]
    const float* __restrict__ xp_s,     // [64][3072]
    const float* __restrict__ w_hh,     // [3072][1024]
    const float* __restrict__ b_hh,     // [3072]
    float* __restrict__ h_out)          // [64][1024]
{
    __shared__ float4 ws4[12 * 256];    // 48 KB: row r (=gate*4+jloc), 256 f4 slots
    __shared__ float4 hs4[64 * 64];     // 64 KB: row b, 64 f4 slots (xor-swizzled)

    const int t  = threadIdx.x;
    const int jb = blockIdx.x;          // 0..255
    const int b  = t & 63;
    const int jj = t >> 6;              // 0..3 (== wave id)
    const int bx = b & 7;               // xor key

    // stage w_hh rows: row q -> gate q>>2, jloc q&3
#pragma unroll
    for (int q = 0; q < 12; ++q) {
        int grow = (q >> 2) * GRU_H + jb * 4 + (q & 3);
        ws4[q * 256 + t] = reinterpret_cast<const float4*>(
            w_hh + (size_t)grow * GRU_H)[t];
    }

    float ar = 0.f, az = 0.f, an = 0.f;

    for (int c = 0; c < 4; ++c) {
        __syncthreads();   // previous chunk fully consumed (and covers w-stage)
        // stage h chunk c: 4096 f4; each wave writes whole rows, slot = lane
#pragma unroll
        for (int q = 0; q < 16; ++q) {
            int f    = q * 256 + t;
            int row  = f >> 6;           // 0..63
            int slot = f & 63;
            hs4[row * 64 + (slot ^ (row & 7))] = reinterpret_cast<const float4*>(
                h_in + (size_t)row * GRU_H + c * 256)[slot];
        }
        __syncthreads();

        const float4* wr = ws4 + (0 + jj) * 256 + c * 64;
        const float4* wz = ws4 + (4 + jj) * 256 + c * 64;
        const float4* wn = ws4 + (8 + jj) * 256 + c * 64;
        const float4* hb = hs4 + b * 64;

#pragma unroll 8
        for (int s = 0; s < 64; ++s) {
            float4 h4 = hb[s ^ bx];
            float4 r4 = wr[s];
            float4 z4 = wz[s];
            float4 n4 = wn[s];
            ar = fmaf(h4.x, r4.x, ar); ar = fmaf(h4.y, r4.y, ar);
            ar = fmaf(h4.z, r4.z, ar); ar = fmaf(h4.w, r4.w, ar);
            az = fmaf(h4.x, z4.x, az); az = fmaf(h4.y, z4.y, az);
            az = fmaf(h4.z, z4.z, az); az = fmaf(h4.w, z4.w, az);
            an = fmaf(h4.x, n4.x, an); an = fmaf(h4.y, n4.y, an);
            an = fmaf(h4.z, n4.z, an); an = fmaf(h4.w, n4.w, an);
        }
    }

    const int j = jb * 4 + jj;

    float hr = ar + b_hh[j];
    float hz = az + b_hh[GRU_H + j];
    float hn = an + b_hh[2 * GRU_H + j];

    const float* xrow = xp_s + (size_t)b * GRU_G;
    float xr = xrow[j];
    float xz = xrow[GRU_H + j];
    float xn = xrow[2 * GRU_H + j];

    float r = 1.f / (1.f + expf(-(xr + hr)));
    float z = 1.f / (1.f + expf(-(xz + hz)));
    float n = tanhf(xn + r * hn);

    float hprev = h_in[(size_t)b * GRU_H + j];
    h_out[(size_t)b * GRU_H + j] = (1.f - z) * n + z * hprev;
}

// ---------------------------------------------------------------------------
// Launch
// ---------------------------------------------------------------------------
extern "C" void kernel_launch(void* const* d_in, const int* in_sizes, int n_in,
                              void* d_out, int out_size, void* d_ws, size_t ws_size,
                              hipStream_t stream) {
    const int*   tokens = (const int*)  d_in[0];
    const float* emb    = (const float*)d_in[1];
    const float* w_ih   = (const float*)d_in[2];
    const float* w_hh   = (const float*)d_in[3];
    const float* b_ih   = (const float*)d_in[4];
    const float* b_hh   = (const float*)d_in[5];
    float* out = (float*)d_out;

    float* xproj = (float*)d_ws;                                   // 96 MB
    float* h0    = xproj + (size_t)GRU_S * GRU_B * GRU_G;
    float* h1    = h0 + (size_t)GRU_B * GRU_H;

    hipMemsetAsync(h0, 0, (size_t)GRU_B * GRU_H * sizeof(float), stream);

    {
        dim3 grid(GRU_B * GRU_S / 128, GRU_G / 128);   // 64 x 24
        xproj_gemm2<<<grid, 256, 0, stream>>>(tokens, emb, w_ih, b_ih, xproj);
    }

    for (int s = 0; s < GRU_S; ++s) {
        const float* hin  = (s & 1) ? h1 : h0;
        float*       hout = (s == GRU_S - 1) ? out : ((s & 1) ? h0 : h1);
        const float* xps  = xproj + (size_t)s * GRU_B * GRU_G;
        gru_step2<<<256, 256, 0, stream>>>(hin, xps, w_hh, b_hh, hout);
    }
}

// Round 3
// 2356.351 us; speedup vs baseline: 2.5463x; 1.5723x over previous
//
#include <hip/hip_runtime.h>
#include <hip/hip_bf16.h>
#include <hip/hip_cooperative_groups.h>
#include <math.h>

// B=64, S=128, V=50257, E=1024, H=1024, G=3H=3072
#define GRU_B 64
#define GRU_S 128
#define GRU_E 1024
#define GRU_H 1024
#define GRU_G 3072

typedef _Float16 half8 __attribute__((ext_vector_type(8)));
typedef _Float16 half4v __attribute__((ext_vector_type(4)));
typedef float floatx4 __attribute__((ext_vector_type(4)));

// ---------------------------------------------------------------------------
// Phase 1 (unchanged from R2): x_proj = emb[tok] @ w_ih^T + b_ih
// ---------------------------------------------------------------------------
__global__ __launch_bounds__(256) void xproj_gemm2(
    const int* __restrict__ tokens,     // [B][S]
    const float* __restrict__ emb,      // [V][E]
    const float* __restrict__ w_ih,     // [G][E]
    const float* __restrict__ b_ih,     // [G]
    float* __restrict__ xproj)          // [M][G] == [S][B][G]
{
    __shared__ float As[32][132];
    __shared__ float Bs[32][132];
    __shared__ int   toks[128];

    const int t  = threadIdx.x;
    const int m0 = blockIdx.x * 128;
    const int n0 = blockIdx.y * 128;

    if (t < 128) {
        int m  = m0 + t;
        int s_ = m >> 6;
        int b_ = m & 63;
        toks[t] = tokens[b_ * GRU_S + s_];
    }

    const int tm = t >> 4;
    const int tn = t & 15;

    float acc[8][8] = {};

    const int srow_base = t >> 3;
    const int sc4       = t & 7;

    for (int k0 = 0; k0 < GRU_E; k0 += 32) {
        __syncthreads();
#pragma unroll
        for (int q = 0; q < 4; ++q) {
            int row = q * 32 + srow_base;
            const float4 av = reinterpret_cast<const float4*>(
                emb + (size_t)toks[row] * GRU_E + k0)[sc4];
            const float4 bv = reinterpret_cast<const float4*>(
                w_ih + (size_t)(n0 + row) * GRU_E + k0)[sc4];
            int kk = sc4 * 4;
            As[kk+0][row] = av.x; As[kk+1][row] = av.y;
            As[kk+2][row] = av.z; As[kk+3][row] = av.w;
            Bs[kk+0][row] = bv.x; Bs[kk+1][row] = bv.y;
            Bs[kk+2][row] = bv.z; Bs[kk+3][row] = bv.w;
        }
        __syncthreads();

#pragma unroll 8
        for (int kk = 0; kk < 32; ++kk) {
            float a[8], bb[8];
            *reinterpret_cast<float4*>(&a[0])  = *reinterpret_cast<const float4*>(&As[kk][tm*8]);
            *reinterpret_cast<float4*>(&a[4])  = *reinterpret_cast<const float4*>(&As[kk][tm*8+4]);
            *reinterpret_cast<float4*>(&bb[0]) = *reinterpret_cast<const float4*>(&Bs[kk][tn*8]);
            *reinterpret_cast<float4*>(&bb[4]) = *reinterpret_cast<const float4*>(&Bs[kk][tn*8+4]);
#pragma unroll
            for (int i = 0; i < 8; ++i)
#pragma unroll
                for (int j = 0; j < 8; ++j)
                    acc[i][j] = fmaf(a[i], bb[j], acc[i][j]);
        }
    }

    float bias[8];
#pragma unroll
    for (int j = 0; j < 8; ++j) bias[j] = b_ih[n0 + tn*8 + j];

#pragma unroll
    for (int i = 0; i < 8; ++i) {
        int m = m0 + tm*8 + i;
        float4* dst = reinterpret_cast<float4*>(xproj + (size_t)m * GRU_G + n0 + tn*8);
        dst[0] = make_float4(acc[i][0]+bias[0], acc[i][1]+bias[1],
                             acc[i][2]+bias[2], acc[i][3]+bias[3]);
        dst[1] = make_float4(acc[i][4]+bias[4], acc[i][5]+bias[5],
                             acc[i][6]+bias[6], acc[i][7]+bias[7]);
    }
}

// ---------------------------------------------------------------------------
// Phase 2: persistent cooperative GRU.
// 64 blocks x 256 threads. Block jb owns j = jb*16 + [0,16) for all 3 gates:
// 48 w_hh rows, converted fp32->fp16 ONCE into 96 KB LDS (XOR-swizzled so the
// stride-2048B ds_read_b128 B-frag reads are 2-way, i.e. free).
// Per step: 64x48x1024 fp16 MFMA (A = broadcast h fp16, read from global),
// fused gate epilogue (h_prev kept fp32 in regs), write h fp16 to the
// ping-pong broadcast buffer, grid.sync().
// n-tile layout: rows [0,16)=gate r, [16,32)=gate z, [32,48)=gate n, so each
// lane's acc0/acc1/acc2 hold r/z/n for the SAME (b,j) -> no cross-lane.
// ---------------------------------------------------------------------------
__global__ __launch_bounds__(256) void gru_persist(
    const float* __restrict__ xproj,    // [S][B][G]
    const float* __restrict__ w_hh,     // [G][H]
    const float* __restrict__ b_hh,     // [G]
    _Float16* __restrict__ hb,          // 2 buffers of [64][1024] fp16
    float* __restrict__ out)            // [64][1024]
{
    __shared__ __attribute__((aligned(16))) _Float16 wlds[48 * 1024];  // 96 KB

    auto grid = cooperative_groups::this_grid();

    const int t   = threadIdx.x;
    const int jb  = blockIdx.x;         // 0..63
    const int l   = t & 63;
    const int wid = t >> 6;             // wave id = m-tile
    const int m0  = wid * 16;

    // ---- stage W: 48 rows (gate*16+jloc), fp32 -> fp16, swizzled ----
    {
        char* wb = reinterpret_cast<char*>(wlds);
        for (int r = 0; r < 48; ++r) {
            int grow = (r >> 4) * GRU_H + jb * 16 + (r & 15);
            float4 v = reinterpret_cast<const float4*>(
                w_hh + (size_t)grow * GRU_H)[t];
            half4v hv;
            hv.x = (_Float16)v.x; hv.y = (_Float16)v.y;
            hv.z = (_Float16)v.z; hv.w = (_Float16)v.w;
            int g = (t >> 1) ^ (r & 7);
            *reinterpret_cast<half4v*>(wb + r * 2048 + g * 16 + (t & 1) * 8) = hv;
        }
    }

    // ---- zero broadcast buffer 0 (h(0) = 0); ws is poisoned, not zeroed ----
    {
        uint* z = reinterpret_cast<uint*>(hb);   // buf0 = 32768 uints
        for (int i = jb * 256 + t; i < 32768; i += 64 * 256) z[i] = 0;
    }

    // ---- per-thread constants ----
    const int jl   = l & 15;
    const int qrow = (l >> 4) * 4;           // C-row base within m-tile
    const int j    = jb * 16 + jl;
    const float bhr = b_hh[j];
    const float bhz = b_hh[GRU_H + j];
    const float bhn = b_hh[2 * GRU_H + j];

    const int arow  = m0 + (l & 15);         // A-frag h row
    const int akoff = (l >> 4) * 8;          // A-frag k offset (elements)
    const int sk    = jl & 7;                // B swizzle key (same all n-tiles)
    const char* wb  = reinterpret_cast<const char*>(wlds);
    const int bbase0 = (0 * 16 + jl) * 2048;
    const int bbase1 = (1 * 16 + jl) * 2048;
    const int bbase2 = (2 * 16 + jl) * 2048;

    float hp[4] = {0.f, 0.f, 0.f, 0.f};

    grid.sync();   // W staged everywhere, hbuf0 zeroed

    for (int s = 0; s < GRU_S; ++s) {
        const _Float16* hc = hb + (size_t)(s & 1) * (GRU_B * GRU_H);
        _Float16*       hn = hb + (size_t)((s + 1) & 1) * (GRU_B * GRU_H);

        // prefetch x_proj gate inputs for this step (independent of h)
        float xr[4], xz[4], xnn[4];
        const float* xpS = xproj + (size_t)s * (GRU_B * GRU_G);
#pragma unroll
        for (int q = 0; q < 4; ++q) {
            const float* row = xpS + (size_t)(m0 + qrow + q) * GRU_G;
            xr[q]  = row[j];
            xz[q]  = row[GRU_H + j];
            xnn[q] = row[2 * GRU_H + j];
        }

        floatx4 acc0 = {0.f, 0.f, 0.f, 0.f};
        floatx4 acc1 = {0.f, 0.f, 0.f, 0.f};
        floatx4 acc2 = {0.f, 0.f, 0.f, 0.f};

        const _Float16* aptr = hc + (size_t)arow * GRU_H + akoff;

#pragma unroll 4
        for (int k0 = 0; k0 < GRU_H; k0 += 32) {
            half8 a = *reinterpret_cast<const half8*>(aptr + k0);
            int g = ((k0 >> 3) + (l >> 4)) ^ sk;
            half8 b0 = *reinterpret_cast<const half8*>(wb + bbase0 + g * 16);
            half8 b1 = *reinterpret_cast<const half8*>(wb + bbase1 + g * 16);
            half8 b2 = *reinterpret_cast<const half8*>(wb + bbase2 + g * 16);
            acc0 = __builtin_amdgcn_mfma_f32_16x16x32_f16(a, b0, acc0, 0, 0, 0);
            acc1 = __builtin_amdgcn_mfma_f32_16x16x32_f16(a, b1, acc1, 0, 0, 0);
            acc2 = __builtin_amdgcn_mfma_f32_16x16x32_f16(a, b2, acc2, 0, 0, 0);
        }

        // fused gate epilogue; h_prev stays fp32 in regs
#pragma unroll
        for (int q = 0; q < 4; ++q) {
            float r  = 1.f / (1.f + __expf(-(xr[q] + acc0[q] + bhr)));
            float zg = 1.f / (1.f + __expf(-(xz[q] + acc1[q] + bhz)));
            float pre = xnn[q] + r * (acc2[q] + bhn);
            pre = fminf(fmaxf(pre, -15.f), 15.f);
            float e2 = __expf(2.f * pre);
            float ng = (e2 - 1.f) / (e2 + 1.f);
            float h  = (1.f - zg) * ng + zg * hp[q];
            hp[q] = h;
            hn[(size_t)(m0 + qrow + q) * GRU_H + j] = (_Float16)h;
        }

        grid.sync();
    }

    // final hidden state -> output (fp32)
#pragma unroll
    for (int q = 0; q < 4; ++q)
        out[(size_t)(m0 + qrow + q) * GRU_H + j] = hp[q];
}

// ---------------------------------------------------------------------------
// Launch
// ---------------------------------------------------------------------------
extern "C" void kernel_launch(void* const* d_in, const int* in_sizes, int n_in,
                              void* d_out, int out_size, void* d_ws, size_t ws_size,
                              hipStream_t stream) {
    const int*   tokens = (const int*)  d_in[0];
    const float* emb    = (const float*)d_in[1];
    const float* w_ih   = (const float*)d_in[2];
    const float* w_hh   = (const float*)d_in[3];
    const float* b_ih   = (const float*)d_in[4];
    const float* b_hh   = (const float*)d_in[5];
    float* out = (float*)d_out;

    float*    xproj = (float*)d_ws;                                  // 96 MB
    _Float16* hb    = (_Float16*)(xproj + (size_t)GRU_S * GRU_B * GRU_G);  // 256 KB

    {
        dim3 grid(GRU_B * GRU_S / 128, GRU_G / 128);   // 64 x 24
        xproj_gemm2<<<grid, 256, 0, stream>>>(tokens, emb, w_ih, b_ih, xproj);
    }

    {
        const float* xp_a = xproj;
        const float* whh_a = w_hh;
        const float* bhh_a = b_hh;
        _Float16* hb_a = hb;
        float* out_a = out;
        void* args[] = { (void*)&xp_a, (void*)&whh_a, (void*)&bhh_a,
                         (void*)&hb_a, (void*)&out_a };
        hipLaunchCooperativeKernel((void*)gru_persist, dim3(64), dim3(256),
                                   args, 0, stream);
    }
}

// Round 4
// 1355.901 us; speedup vs baseline: 4.4250x; 1.7378x over previous
//
#include <hip/hip_runtime.h>
#include <hip/hip_bf16.h>
#include <math.h>

// B=64, S=128, V=50257, E=1024, H=1024, G=3H=3072
#define GRU_B 64
#define GRU_S 128
#define GRU_E 1024
#define GRU_H 1024
#define GRU_G 3072

typedef _Float16 half8 __attribute__((ext_vector_type(8)));
typedef _Float16 half4v __attribute__((ext_vector_type(4)));
typedef float floatx4 __attribute__((ext_vector_type(4)));

__device__ __forceinline__ half8 cvt_h8(float4 a, float4 b) {
    half8 r;
    r[0] = (_Float16)a.x; r[1] = (_Float16)a.y;
    r[2] = (_Float16)a.z; r[3] = (_Float16)a.w;
    r[4] = (_Float16)b.x; r[5] = (_Float16)b.y;
    r[6] = (_Float16)b.z; r[7] = (_Float16)b.w;
    return r;
}

// ---------------------------------------------------------------------------
// Phase 1: x_proj = emb[tok] @ w_ih^T + b_ih via fp16 MFMA (fp32 accum).
// 128x128 C-tile, BK=32, 4 waves (2x2), each wave 64x64 via 4x4 16x16x32
// frags. LDS [row][k] fp16 with granule swizzle g^=(row>>1)&3 (2-way reads).
// ---------------------------------------------------------------------------
__global__ __launch_bounds__(256) void xproj_mfma(
    const int* __restrict__ tokens,     // [B][S]
    const float* __restrict__ emb,      // [V][E]
    const float* __restrict__ w_ih,     // [G][E]
    const float* __restrict__ b_ih,     // [G]
    float* __restrict__ xproj)          // [M][G], m = s*64+b
{
    __shared__ __attribute__((aligned(16))) _Float16 Al[128 * 32];
    __shared__ __attribute__((aligned(16))) _Float16 Bl[128 * 32];
    __shared__ int toks[128];

    const int t  = threadIdx.x;
    const int m0 = blockIdx.x * 128;
    const int n0 = blockIdx.y * 128;

    if (t < 128) {
        int m = m0 + t;
        toks[t] = tokens[(m & 63) * GRU_S + (m >> 6)];   // tokens[b][s]
    }

    const int wid = t >> 6;
    const int l   = t & 63;
    const int wm  = (wid >> 1) * 64;
    const int wn  = (wid & 1) * 64;

    // staging: row sr = t>>1, k-half (t&1)*16
    const int sr   = t >> 1;
    const int skw  = (sr >> 1) & 3;
    const int gb   = (t & 1) * 2;

    // frag read params
    const int fr   = l & 15;
    const int ag   = l >> 4;
    const int skey = (fr >> 1) & 3;
    const int gfr  = (ag ^ skey) * 16;

    char* ab = reinterpret_cast<char*>(Al);
    char* bb = reinterpret_cast<char*>(Bl);

    floatx4 acc[4][4];
#pragma unroll
    for (int i = 0; i < 4; ++i)
#pragma unroll
        for (int j = 0; j < 4; ++j)
            acc[i][j] = (floatx4){0.f, 0.f, 0.f, 0.f};

    for (int k0 = 0; k0 < GRU_E; k0 += 32) {
        __syncthreads();   // prev chunk consumed (covers toks on first iter)
        {
            const float4* asrc = reinterpret_cast<const float4*>(
                emb + (size_t)toks[sr] * GRU_E + k0 + (t & 1) * 16);
            const float4* bsrc = reinterpret_cast<const float4*>(
                w_ih + (size_t)(n0 + sr) * GRU_E + k0 + (t & 1) * 16);
            float4 a0 = asrc[0], a1 = asrc[1], a2 = asrc[2], a3 = asrc[3];
            float4 b0 = bsrc[0], b1 = bsrc[1], b2 = bsrc[2], b3 = bsrc[3];
            *reinterpret_cast<half8*>(ab + sr * 64 + ((gb + 0) ^ skw) * 16) = cvt_h8(a0, a1);
            *reinterpret_cast<half8*>(ab + sr * 64 + ((gb + 1) ^ skw) * 16) = cvt_h8(a2, a3);
            *reinterpret_cast<half8*>(bb + sr * 64 + ((gb + 0) ^ skw) * 16) = cvt_h8(b0, b1);
            *reinterpret_cast<half8*>(bb + sr * 64 + ((gb + 1) ^ skw) * 16) = cvt_h8(b2, b3);
        }
        __syncthreads();

        half8 a4[4], b4[4];
#pragma unroll
        for (int mi = 0; mi < 4; ++mi)
            a4[mi] = *reinterpret_cast<const half8*>(ab + (wm + mi * 16 + fr) * 64 + gfr);
#pragma unroll
        for (int ni = 0; ni < 4; ++ni)
            b4[ni] = *reinterpret_cast<const half8*>(bb + (wn + ni * 16 + fr) * 64 + gfr);
#pragma unroll
        for (int mi = 0; mi < 4; ++mi)
#pragma unroll
            for (int ni = 0; ni < 4; ++ni)
                acc[mi][ni] = __builtin_amdgcn_mfma_f32_16x16x32_f16(
                    a4[mi], b4[ni], acc[mi][ni], 0, 0, 0);
    }

    const int cr = (l >> 4) * 4;
    const int cc = l & 15;
#pragma unroll
    for (int ni = 0; ni < 4; ++ni) {
        int n = n0 + wn + ni * 16 + cc;
        float bias = b_ih[n];
#pragma unroll
        for (int mi = 0; mi < 4; ++mi) {
#pragma unroll
            for (int q = 0; q < 4; ++q) {
                int m = m0 + wm + mi * 16 + cr + q;
                xproj[(size_t)m * GRU_G + n] = acc[mi][ni][q] + bias;
            }
        }
    }
}

// ---------------------------------------------------------------------------
// Phase 2: persistent GRU with custom agent-scope grid barrier.
// Structure identical to R3 (W fp16 in 96 KB swizzled LDS, 64x48x1024 fp16
// MFMA per step, fused gates, h_prev fp32 in regs), but:
//  - grid.sync() -> release-fence + atomicAdd + relaxed spin + acquire-fence
//  - xproj gate inputs for step s+1 prefetched BEFORE the barrier
// ---------------------------------------------------------------------------
__device__ __forceinline__ void grid_barrier(int* ctr, int* flag, int target, int t) {
    __syncthreads();
    if (t == 0) {
        __builtin_amdgcn_fence(__ATOMIC_RELEASE, "agent");   // waitcnt + wbl2
        int old = __hip_atomic_fetch_add(ctr, 1, __ATOMIC_RELAXED,
                                         __HIP_MEMORY_SCOPE_AGENT);
        if (old == target * 64 - 1)
            __hip_atomic_store(flag, target, __ATOMIC_RELAXED,
                               __HIP_MEMORY_SCOPE_AGENT);
        while (__hip_atomic_load(flag, __ATOMIC_RELAXED,
                                 __HIP_MEMORY_SCOPE_AGENT) < target)
            __builtin_amdgcn_s_sleep(2);
        __builtin_amdgcn_fence(__ATOMIC_ACQUIRE, "agent");   // inv L1/L2
    }
    __syncthreads();
}

__global__ __launch_bounds__(256) void gru_persist(
    const float* __restrict__ xproj,    // [S][B][G]
    const float* __restrict__ w_hh,     // [G][H]
    const float* __restrict__ b_hh,     // [G]
    _Float16* __restrict__ hb,          // 2 x [64][1024] fp16
    float* __restrict__ out,            // [64][1024]
    int* __restrict__ bar)              // [0]=ctr, [1]=flag (zeroed by host)
{
    __shared__ __attribute__((aligned(16))) _Float16 wlds[48 * 1024];  // 96 KB

    const int t   = threadIdx.x;
    const int jb  = blockIdx.x;         // 0..63
    const int l   = t & 63;
    const int wid = t >> 6;
    const int m0  = wid * 16;

    int* ctr  = bar;
    int* flag = bar + 1;

    // ---- stage W: 48 rows (gate*16+jloc), fp32 -> fp16, swizzled ----
    {
        char* wb = reinterpret_cast<char*>(wlds);
        for (int r = 0; r < 48; ++r) {
            int grow = (r >> 4) * GRU_H + jb * 16 + (r & 15);
            float4 v = reinterpret_cast<const float4*>(
                w_hh + (size_t)grow * GRU_H)[t];
            half4v hv;
            hv.x = (_Float16)v.x; hv.y = (_Float16)v.y;
            hv.z = (_Float16)v.z; hv.w = (_Float16)v.w;
            int g = (t >> 1) ^ (r & 7);
            *reinterpret_cast<half4v*>(wb + r * 2048 + g * 16 + (t & 1) * 8) = hv;
        }
    }

    // ---- zero broadcast buffer 0 (h(0)=0) ----
    {
        uint* z = reinterpret_cast<uint*>(hb);
        for (int i = jb * 256 + t; i < 32768; i += 64 * 256) z[i] = 0;
    }

    // ---- per-thread constants ----
    const int jl   = l & 15;
    const int qrow = (l >> 4) * 4;
    const int j    = jb * 16 + jl;
    const float bhr = b_hh[j];
    const float bhz = b_hh[GRU_H + j];
    const float bhn = b_hh[2 * GRU_H + j];

    const int arow  = m0 + (l & 15);
    const int akoff = (l >> 4) * 8;
    const int sk    = jl & 7;
    const char* wb  = reinterpret_cast<const char*>(wlds);
    const int bbase0 = (0 * 16 + jl) * 2048;
    const int bbase1 = (1 * 16 + jl) * 2048;
    const int bbase2 = (2 * 16 + jl) * 2048;

    float hp[4] = {0.f, 0.f, 0.f, 0.f};

    // prefetch x_proj for step 0 (read-only, no cross-block dep)
    float xr[4], xz[4], xnn[4];
#pragma unroll
    for (int q = 0; q < 4; ++q) {
        const float* row = xproj + (size_t)(m0 + qrow + q) * GRU_G;
        xr[q]  = row[j];
        xz[q]  = row[GRU_H + j];
        xnn[q] = row[2 * GRU_H + j];
    }

    grid_barrier(ctr, flag, 1, t);      // h zeroed everywhere

    for (int s = 0; s < GRU_S; ++s) {
        const _Float16* hc = hb + (size_t)(s & 1) * (GRU_B * GRU_H);
        _Float16*       hn = hb + (size_t)((s + 1) & 1) * (GRU_B * GRU_H);

        floatx4 acc0 = {0.f, 0.f, 0.f, 0.f};
        floatx4 acc1 = {0.f, 0.f, 0.f, 0.f};
        floatx4 acc2 = {0.f, 0.f, 0.f, 0.f};

        const _Float16* aptr = hc + (size_t)arow * GRU_H + akoff;

#pragma unroll 4
        for (int k0 = 0; k0 < GRU_H; k0 += 32) {
            half8 a = *reinterpret_cast<const half8*>(aptr + k0);
            int g = ((k0 >> 3) + (l >> 4)) ^ sk;
            half8 b0 = *reinterpret_cast<const half8*>(wb + bbase0 + g * 16);
            half8 b1 = *reinterpret_cast<const half8*>(wb + bbase1 + g * 16);
            half8 b2 = *reinterpret_cast<const half8*>(wb + bbase2 + g * 16);
            acc0 = __builtin_amdgcn_mfma_f32_16x16x32_f16(a, b0, acc0, 0, 0, 0);
            acc1 = __builtin_amdgcn_mfma_f32_16x16x32_f16(a, b1, acc1, 0, 0, 0);
            acc2 = __builtin_amdgcn_mfma_f32_16x16x32_f16(a, b2, acc2, 0, 0, 0);
        }

        // fused gate epilogue
#pragma unroll
        for (int q = 0; q < 4; ++q) {
            float r  = 1.f / (1.f + __expf(-(xr[q] + acc0[q] + bhr)));
            float zg = 1.f / (1.f + __expf(-(xz[q] + acc1[q] + bhz)));
            float pre = xnn[q] + r * (acc2[q] + bhn);
            pre = fminf(fmaxf(pre, -15.f), 15.f);
            float e2 = __expf(2.f * pre);
            float ng = (e2 - 1.f) / (e2 + 1.f);
            float h  = (1.f - zg) * ng + zg * hp[q];
            hp[q] = h;
            hn[(size_t)(m0 + qrow + q) * GRU_H + j] = (_Float16)h;
        }

        if (s + 1 < GRU_S) {
            // prefetch x_proj for step s+1 BEFORE the barrier (hides HBM latency)
            const float* xpS = xproj + (size_t)(s + 1) * (GRU_B * GRU_G);
#pragma unroll
            for (int q = 0; q < 4; ++q) {
                const float* row = xpS + (size_t)(m0 + qrow + q) * GRU_G;
                xr[q]  = row[j];
                xz[q]  = row[GRU_H + j];
                xnn[q] = row[2 * GRU_H + j];
            }
            grid_barrier(ctr, flag, s + 2, t);
        }
    }

    // final hidden state -> output (fp32)
#pragma unroll
    for (int q = 0; q < 4; ++q)
        out[(size_t)(m0 + qrow + q) * GRU_H + j] = hp[q];
}

// ---------------------------------------------------------------------------
// Launch
// ---------------------------------------------------------------------------
extern "C" void kernel_launch(void* const* d_in, const int* in_sizes, int n_in,
                              void* d_out, int out_size, void* d_ws, size_t ws_size,
                              hipStream_t stream) {
    const int*   tokens = (const int*)  d_in[0];
    const float* emb    = (const float*)d_in[1];
    const float* w_ih   = (const float*)d_in[2];
    const float* w_hh   = (const float*)d_in[3];
    const float* b_ih   = (const float*)d_in[4];
    const float* b_hh   = (const float*)d_in[5];
    float* out = (float*)d_out;

    float*    xproj = (float*)d_ws;                                       // 96 MB
    _Float16* hb    = (_Float16*)(xproj + (size_t)GRU_S * GRU_B * GRU_G); // 256 KB
    int*      bar   = (int*)(hb + 2 * (size_t)GRU_B * GRU_H);

    hipMemsetAsync(bar, 0, 2 * sizeof(int), stream);

    {
        dim3 grid(GRU_B * GRU_S / 128, GRU_G / 128);   // 64 x 24
        xproj_mfma<<<grid, 256, 0, stream>>>(tokens, emb, w_ih, b_ih, xproj);
    }

    {
        const float* xp_a = xproj;
        const float* whh_a = w_hh;
        const float* bhh_a = b_hh;
        _Float16* hb_a = hb;
        float* out_a = out;
        int* bar_a = bar;
        void* args[] = { (void*)&xp_a, (void*)&whh_a, (void*)&bhh_a,
                         (void*)&hb_a, (void*)&out_a, (void*)&bar_a };
        hipLaunchCooperativeKernel((void*)gru_persist, dim3(64), dim3(256),
                                   args, 0, stream);
    }
}